// Round 1
// baseline (239.224 us; speedup 1.0000x reference)
//
#include <hip/hip_runtime.h>
#include <float.h>
#include <math.h>

#define BB 32
#define NN 1024
#define DD 128
#define HH 128
#define KK 5

// ---------------- 1. row L2-normalize: xn = x / max(||x||, 1e-12) --------
// one wave per row (128 f32 = 2/lane), 4 waves per block
__global__ __launch_bounds__(256) void k_norm(const float* __restrict__ x,
                                              float* __restrict__ xn) {
    int row  = blockIdx.x * 4 + (threadIdx.x >> 6);
    int lane = threadIdx.x & 63;
    const float* xr = x + (size_t)row * DD;
    float2 v = *reinterpret_cast<const float2*>(xr + lane * 2);
    float ss = v.x * v.x + v.y * v.y;
#pragma unroll
    for (int o = 32; o >= 1; o >>= 1) ss += __shfl_xor(ss, o);
    float inv = 1.0f / fmaxf(sqrtf(ss), 1e-12f);
    float2 ov = make_float2(v.x * inv, v.y * inv);
    *reinterpret_cast<float2*>(xn + (size_t)row * DD + lane * 2) = ov;
}

// ---------------- shared staging: 128 rows x 64 k -> LDS k-major ---------
// s[k][r], r stride 132 (pad keeps float4 reads 16B-aligned, spreads banks)
__device__ __forceinline__ void stage_T64(const float* __restrict__ g,
                                          float (*s)[132], int tid) {
    int kv = tid & 15;   // which float4 of the 64-k chunk
    int r0 = tid >> 4;   // 16 rows per pass
#pragma unroll
    for (int p = 0; p < 8; ++p) {
        int r = r0 + (p << 4);
        const float4 v = *reinterpret_cast<const float4*>(g + (size_t)r * DD + (kv << 2));
        int k = kv << 2;
        s[k + 0][r] = v.x; s[k + 1][r] = v.y; s[k + 2][r] = v.z; s[k + 3][r] = v.w;
    }
}

// ---------------- 2. sim = xn_b . xn_b^T, one 128x128 tile per block ----
__global__ __launch_bounds__(256, 2) void k_sim(const float* __restrict__ xn,
                                                float* __restrict__ sim, int b0) {
    int t  = blockIdx.x;
    int bl = t >> 6;             // batch within slice
    int tt = t & 63;
    int rt = (tt >> 3) << 7;     // row-tile origin
    int ct = (tt & 7) << 7;      // col-tile origin
    const float* Ab = xn + ((size_t)(b0 + bl) * NN + rt) * DD;
    const float* Bb = xn + ((size_t)(b0 + bl) * NN + ct) * DD;
    float* C = sim + ((size_t)bl * NN + rt) * NN + ct;

    __shared__ float As[64][132];
    __shared__ float Bs[64][132];
    int tid = threadIdx.x;
    int tr  = (tid >> 4) << 3;   // row in tile (0..120)
    int tc  = (tid & 15) << 3;   // col in tile

    float acc[8][8];
#pragma unroll
    for (int i = 0; i < 8; ++i)
#pragma unroll
        for (int j = 0; j < 8; ++j) acc[i][j] = 0.f;

#pragma unroll
    for (int kc = 0; kc < 2; ++kc) {
        if (kc) __syncthreads();
        stage_T64(Ab + kc * 64, As, tid);
        stage_T64(Bb + kc * 64, Bs, tid);
        __syncthreads();
#pragma unroll 4
        for (int k = 0; k < 64; ++k) {
            const float4 a0 = *reinterpret_cast<const float4*>(&As[k][tr]);
            const float4 a1 = *reinterpret_cast<const float4*>(&As[k][tr + 4]);
            const float4 b0v = *reinterpret_cast<const float4*>(&Bs[k][tc]);
            const float4 b1v = *reinterpret_cast<const float4*>(&Bs[k][tc + 4]);
            const float av[8] = {a0.x, a0.y, a0.z, a0.w, a1.x, a1.y, a1.z, a1.w};
            const float bw[8] = {b0v.x, b0v.y, b0v.z, b0v.w, b1v.x, b1v.y, b1v.z, b1v.w};
#pragma unroll
            for (int ii = 0; ii < 8; ++ii)
#pragma unroll
                for (int jj = 0; jj < 8; ++jj)
                    acc[ii][jj] = fmaf(av[ii], bw[jj], acc[ii][jj]);
        }
    }
#pragma unroll
    for (int i = 0; i < 8; ++i) {
        float* cr = C + (size_t)(tr + i) * NN + tc;
        *reinterpret_cast<float4*>(cr)     = make_float4(acc[i][0], acc[i][1], acc[i][2], acc[i][3]);
        *reinterpret_cast<float4*>(cr + 4) = make_float4(acc[i][4], acc[i][5], acc[i][6], acc[i][7]);
    }
}

// ---------------- 3. top-5 per row (wave per row) ------------------------
// lane holds cols [lane*16, lane*16+16); 5 rounds of (local max -> wave
// argmax with lower-index tie-break, matching lax.top_k) -> mask winner.
__global__ __launch_bounds__(256) void k_topk(const float* __restrict__ sim,
                                              int* __restrict__ idx, int b0) {
    int lrow = blockIdx.x * 4 + (threadIdx.x >> 6);   // row within slice
    int lane = threadIdx.x & 63;
    const float* sr = sim + (size_t)lrow * NN;
    int i = lrow & (NN - 1);                          // within-batch row

    float v[16];
#pragma unroll
    for (int q = 0; q < 4; ++q) {
        float4 f = *reinterpret_cast<const float4*>(sr + lane * 16 + q * 4);
        v[q * 4 + 0] = f.x; v[q * 4 + 1] = f.y; v[q * 4 + 2] = f.z; v[q * 4 + 3] = f.w;
    }
    if ((i >> 4) == lane) {          // mask the diagonal (ref sets it to -1)
        int s = i & 15;
#pragma unroll
        for (int j = 0; j < 16; ++j) if (j == s) v[j] = -FLT_MAX;
    }
    int* op = idx + ((size_t)b0 * NN + lrow) * KK;
#pragma unroll
    for (int t = 0; t < KK; ++t) {
        float bv = v[0]; int bj = 0;
#pragma unroll
        for (int j = 1; j < 16; ++j) if (v[j] > bv) { bv = v[j]; bj = j; }
        int bm = (lane << 4) + bj;
#pragma unroll
        for (int o = 1; o < 64; o <<= 1) {
            float ov = __shfl_xor(bv, o);
            int   om = __shfl_xor(bm, o);
            if (ov > bv || (ov == bv && om < bm)) { bv = ov; bm = om; }
        }
        if ((bm >> 4) == lane) {
            int s = bm & 15;
#pragma unroll
            for (int j = 0; j < 16; ++j) if (j == s) v[j] = -FLT_MAX;
        }
        if (lane == 0) op[t] = bm;
    }
}

// ---------------- 4. aggregate: (h_i + sum_knn h_m) / 6 ------------------
__global__ __launch_bounds__(256) void k_agg(const float* __restrict__ h,
                                             const int* __restrict__ idx,
                                             float* __restrict__ out) {
    int row = blockIdx.x * 2 + (threadIdx.x >> 7);
    int d   = threadIdx.x & 127;
    int b   = row >> 10;
    const float* hb = h + ((size_t)b << 10) * DD;
    const int* ip = idx + (size_t)row * KK;
    float s = h[(size_t)row * DD + d];
#pragma unroll
    for (int t = 0; t < KK; ++t) s += hb[(size_t)ip[t] * DD + d];
    out[(size_t)row * DD + d] = s * (1.0f / 6.0f);
}

// ---------------- 5. out = res + relu(A @ W^T + bias) --------------------
// A: (32768,128), W: (128,128) row-major (h,d). 128 rows per block.
__global__ __launch_bounds__(256, 2) void k_gcn(const float* __restrict__ A,
                                                const float* __restrict__ W,
                                                const float* __restrict__ bias,
                                                const float* __restrict__ res,
                                                float* __restrict__ out) {
    int rt = blockIdx.x << 7;
    const float* Ab = A + (size_t)rt * DD;
    __shared__ float As[64][132];
    __shared__ float Bs[64][132];
    int tid = threadIdx.x;
    int tr  = (tid >> 4) << 3;
    int tc  = (tid & 15) << 3;

    float acc[8][8];
#pragma unroll
    for (int i = 0; i < 8; ++i)
#pragma unroll
        for (int j = 0; j < 8; ++j) acc[i][j] = 0.f;

#pragma unroll
    for (int kc = 0; kc < 2; ++kc) {
        if (kc) __syncthreads();
        stage_T64(Ab + kc * 64, As, tid);
        stage_T64(W + kc * 64, Bs, tid);
        __syncthreads();
#pragma unroll 4
        for (int k = 0; k < 64; ++k) {
            const float4 a0 = *reinterpret_cast<const float4*>(&As[k][tr]);
            const float4 a1 = *reinterpret_cast<const float4*>(&As[k][tr + 4]);
            const float4 b0v = *reinterpret_cast<const float4*>(&Bs[k][tc]);
            const float4 b1v = *reinterpret_cast<const float4*>(&Bs[k][tc + 4]);
            const float av[8] = {a0.x, a0.y, a0.z, a0.w, a1.x, a1.y, a1.z, a1.w};
            const float bw[8] = {b0v.x, b0v.y, b0v.z, b0v.w, b1v.x, b1v.y, b1v.z, b1v.w};
#pragma unroll
            for (int ii = 0; ii < 8; ++ii)
#pragma unroll
                for (int jj = 0; jj < 8; ++jj)
                    acc[ii][jj] = fmaf(av[ii], bw[jj], acc[ii][jj]);
        }
    }
    const float4 bz0 = *reinterpret_cast<const float4*>(bias + tc);
    const float4 bz1 = *reinterpret_cast<const float4*>(bias + tc + 4);
    const float bb[8] = {bz0.x, bz0.y, bz0.z, bz0.w, bz1.x, bz1.y, bz1.z, bz1.w};
#pragma unroll
    for (int i = 0; i < 8; ++i) {
        size_t ro = (size_t)(rt + tr + i) * HH + tc;
        const float4 r0 = *reinterpret_cast<const float4*>(res + ro);
        const float4 r1 = *reinterpret_cast<const float4*>(res + ro + 4);
        float4 o0, o1;
        o0.x = r0.x + fmaxf(acc[i][0] + bb[0], 0.f);
        o0.y = r0.y + fmaxf(acc[i][1] + bb[1], 0.f);
        o0.z = r0.z + fmaxf(acc[i][2] + bb[2], 0.f);
        o0.w = r0.w + fmaxf(acc[i][3] + bb[3], 0.f);
        o1.x = r1.x + fmaxf(acc[i][4] + bb[4], 0.f);
        o1.y = r1.y + fmaxf(acc[i][5] + bb[5], 0.f);
        o1.z = r1.z + fmaxf(acc[i][6] + bb[6], 0.f);
        o1.w = r1.w + fmaxf(acc[i][7] + bb[7], 0.f);
        *reinterpret_cast<float4*>(out + ro)     = o0;
        *reinterpret_cast<float4*>(out + ro + 4) = o1;
    }
}

extern "C" void kernel_launch(void* const* d_in, const int* in_sizes, int n_in,
                              void* d_out, int out_size, void* d_ws, size_t ws_size,
                              hipStream_t stream) {
    const float* x  = (const float*)d_in[0];
    const float* W1 = (const float*)d_in[1];
    const float* b1 = (const float*)d_in[2];
    const float* W2 = (const float*)d_in[3];
    const float* b2 = (const float*)d_in[4];
    float* out = (float*)d_out;

    char* ws = (char*)d_ws;
    size_t xn_b  = (size_t)BB * NN * DD * 4;
    size_t agg_b = (size_t)BB * NN * DD * 4;
    size_t idx_b = (size_t)BB * NN * KK * 4;
    float* xn  = (float*)ws;            ws += xn_b;
    float* agg = (float*)ws;            ws += agg_b;
    int*   idx = (int*)ws;              ws += idx_b;
    float* sim = (float*)ws;
    size_t fixed = xn_b + agg_b + idx_b;
    size_t sim_avail = (ws_size > fixed) ? (ws_size - fixed) : 0;
    int SB = (int)(sim_avail / ((size_t)NN * NN * 4));
    if (SB > BB) SB = BB;
    if (SB < 1) SB = 1;   // below ~55 MB ws this would overflow; assumed OK

    k_norm<<<BB * NN / 4, 256, 0, stream>>>(x, xn);
    for (int b0 = 0; b0 < BB; b0 += SB) {
        int sb = (SB < BB - b0) ? SB : (BB - b0);
        k_sim<<<sb * 64, 256, 0, stream>>>(xn, sim, b0);
        k_topk<<<sb * NN / 4, 256, 0, stream>>>(sim, idx, b0);
    }
    k_agg<<<BB * NN / 2, 256, 0, stream>>>(x, idx, agg);
    k_gcn<<<BB * NN / 128, 256, 0, stream>>>(agg, W1, b1, x, out);
    k_agg<<<BB * NN / 2, 256, 0, stream>>>(out, idx, agg);
    k_gcn<<<BB * NN / 128, 256, 0, stream>>>(agg, W2, b2, out, out);
}

// Round 2
// 209.941 us; speedup vs baseline: 1.1395x; 1.1395x over previous
//
#include <hip/hip_runtime.h>
#include <float.h>
#include <math.h>

#define BB 32
#define NN 1024
#define DD 128
#define HH 128
#define KK 5

// ---------------- 1. row L2-normalize: xn = x / max(||x||, 1e-12) --------
__global__ __launch_bounds__(256) void k_norm(const float* __restrict__ x,
                                              float* __restrict__ xn) {
    int row  = blockIdx.x * 4 + (threadIdx.x >> 6);
    int lane = threadIdx.x & 63;
    const float* xr = x + (size_t)row * DD;
    float2 v = *reinterpret_cast<const float2*>(xr + lane * 2);
    float ss = v.x * v.x + v.y * v.y;
#pragma unroll
    for (int o = 32; o >= 1; o >>= 1) ss += __shfl_xor(ss, o);
    float inv = 1.0f / fmaxf(sqrtf(ss), 1e-12f);
    float2 ov = make_float2(v.x * inv, v.y * inv);
    *reinterpret_cast<float2*>(xn + (size_t)row * DD + lane * 2) = ov;
}

// ------- k_sim staging: 128 rows x 32 k, register prefetch + ds_write ----
__device__ __forceinline__ void ld32(const float* __restrict__ g, int tid,
                                     int kc, float4* r) {
    int kv = tid & 7;           // which float4 of the 32-k chunk
    int r0 = tid >> 3;          // 32 rows per pass
#pragma unroll
    for (int p = 0; p < 4; ++p)
        r[p] = *reinterpret_cast<const float4*>(g + (size_t)(r0 + (p << 5)) * DD +
                                                (kc << 5) + (kv << 2));
}

__device__ __forceinline__ void st32(float (*s)[132], int tid, const float4* r) {
    int k  = (tid & 7) << 2;
    int r0 = tid >> 3;
#pragma unroll
    for (int p = 0; p < 4; ++p) {
        int row = r0 + (p << 5);
        s[k + 0][row] = r[p].x; s[k + 1][row] = r[p].y;
        s[k + 2][row] = r[p].z; s[k + 3][row] = r[p].w;
    }
}

// ---- 2. sim = xn_b . xn_b^T, symmetric: 36 upper-tri 128x128 tiles ------
__global__ __launch_bounds__(256, 4) void k_sim(const float* __restrict__ xn,
                                                float* __restrict__ sim, int b0) {
    int t  = blockIdx.x;
    int bl = t / 36;
    int p  = t - bl * 36;
    int ti = 0;
    while (p >= 8 - ti) { p -= 8 - ti; ++ti; }
    int tj = ti + p;
    int rt = ti << 7, ct = tj << 7;

    const float* Ab = xn + ((size_t)(b0 + bl) * NN + rt) * DD;
    const float* Bb = xn + ((size_t)(b0 + bl) * NN + ct) * DD;
    float* Cb = sim + (size_t)bl * NN * NN;

    __shared__ float As[32][132];
    __shared__ float Bs[32][132];
    int tid = threadIdx.x;
    int tr  = (tid >> 4) << 3;
    int tc  = (tid & 15) << 3;

    float acc[8][8];
#pragma unroll
    for (int i = 0; i < 8; ++i)
#pragma unroll
        for (int j = 0; j < 8; ++j) acc[i][j] = 0.f;

    float4 pa[4], pb[4];
    ld32(Ab, tid, 0, pa);
    ld32(Bb, tid, 0, pb);

#pragma unroll
    for (int kc = 0; kc < 4; ++kc) {
        st32(As, tid, pa);
        st32(Bs, tid, pb);
        __syncthreads();
        if (kc < 3) {                     // prefetch next chunk into regs
            ld32(Ab, tid, kc + 1, pa);
            ld32(Bb, tid, kc + 1, pb);
        }
#pragma unroll 4
        for (int k = 0; k < 32; ++k) {
            const float4 a0 = *reinterpret_cast<const float4*>(&As[k][tr]);
            const float4 a1 = *reinterpret_cast<const float4*>(&As[k][tr + 4]);
            const float4 b0v = *reinterpret_cast<const float4*>(&Bs[k][tc]);
            const float4 b1v = *reinterpret_cast<const float4*>(&Bs[k][tc + 4]);
            const float av[8] = {a0.x, a0.y, a0.z, a0.w, a1.x, a1.y, a1.z, a1.w};
            const float bw[8] = {b0v.x, b0v.y, b0v.z, b0v.w, b1v.x, b1v.y, b1v.z, b1v.w};
#pragma unroll
            for (int ii = 0; ii < 8; ++ii)
#pragma unroll
                for (int jj = 0; jj < 8; ++jj)
                    acc[ii][jj] = fmaf(av[ii], bw[jj], acc[ii][jj]);
        }
        __syncthreads();
    }

    // write (rt,ct) block
#pragma unroll
    for (int i = 0; i < 8; ++i) {
        float* cr = Cb + (size_t)(rt + tr + i) * NN + ct + tc;
        *reinterpret_cast<float4*>(cr)     = make_float4(acc[i][0], acc[i][1], acc[i][2], acc[i][3]);
        *reinterpret_cast<float4*>(cr + 4) = make_float4(acc[i][4], acc[i][5], acc[i][6], acc[i][7]);
    }
    // mirrored (ct,rt) block: column j of acc -> contiguous row
    if (ti != tj) {
#pragma unroll
        for (int j = 0; j < 8; ++j) {
            float* cr = Cb + (size_t)(ct + tc + j) * NN + rt + tr;
            *reinterpret_cast<float4*>(cr)     = make_float4(acc[0][j], acc[1][j], acc[2][j], acc[3][j]);
            *reinterpret_cast<float4*>(cr + 4) = make_float4(acc[4][j], acc[5][j], acc[6][j], acc[7][j]);
        }
    }
}

// ---------------- 3. top-5 per row (wave per row) ------------------------
__global__ __launch_bounds__(256) void k_topk(const float* __restrict__ sim,
                                              int* __restrict__ idx, int b0) {
    int lrow = blockIdx.x * 4 + (threadIdx.x >> 6);
    int lane = threadIdx.x & 63;
    const float* sr = sim + (size_t)lrow * NN;
    int i = lrow & (NN - 1);

    float v[16];
#pragma unroll
    for (int q = 0; q < 4; ++q) {
        float4 f = *reinterpret_cast<const float4*>(sr + lane * 16 + q * 4);
        v[q * 4 + 0] = f.x; v[q * 4 + 1] = f.y; v[q * 4 + 2] = f.z; v[q * 4 + 3] = f.w;
    }
    if ((i >> 4) == lane) {
        int s = i & 15;
#pragma unroll
        for (int j = 0; j < 16; ++j) if (j == s) v[j] = -FLT_MAX;
    }
    int* op = idx + ((size_t)b0 * NN + lrow) * KK;
#pragma unroll
    for (int t = 0; t < KK; ++t) {
        float bv = v[0]; int bj = 0;
#pragma unroll
        for (int j = 1; j < 16; ++j) if (v[j] > bv) { bv = v[j]; bj = j; }
        int bm = (lane << 4) + bj;
#pragma unroll
        for (int o = 1; o < 64; o <<= 1) {
            float ov = __shfl_xor(bv, o);
            int   om = __shfl_xor(bm, o);
            if (ov > bv || (ov == bv && om < bm)) { bv = ov; bm = om; }
        }
        if ((bm >> 4) == lane) {
            int s = bm & 15;
#pragma unroll
            for (int j = 0; j < 16; ++j) if (j == s) v[j] = -FLT_MAX;
        }
        if (lane == 0) op[t] = bm;
    }
}

// ---------------- 4. aggregate: (h_i + sum_knn h_m) / 6 ------------------
__global__ __launch_bounds__(256) void k_agg(const float* __restrict__ h,
                                             const int* __restrict__ idx,
                                             float* __restrict__ out) {
    int row = blockIdx.x * 2 + (threadIdx.x >> 7);
    int d   = threadIdx.x & 127;
    int b   = row >> 10;
    const float* hb = h + ((size_t)b << 10) * DD;
    const int* ip = idx + (size_t)row * KK;
    float s = h[(size_t)row * DD + d];
#pragma unroll
    for (int t = 0; t < KK; ++t) s += hb[(size_t)ip[t] * DD + d];
    out[(size_t)row * DD + d] = s * (1.0f / 6.0f);
}

// -------- gcn staging: 128 rows x 64 k -> LDS k-major (BK=64) ------------
__device__ __forceinline__ void stage_T64(const float* __restrict__ g,
                                          float (*s)[132], int tid) {
    int kv = tid & 15;
    int r0 = tid >> 4;
#pragma unroll
    for (int p = 0; p < 8; ++p) {
        int r = r0 + (p << 4);
        const float4 v = *reinterpret_cast<const float4*>(g + (size_t)r * DD + (kv << 2));
        int k = kv << 2;
        s[k + 0][r] = v.x; s[k + 1][r] = v.y; s[k + 2][r] = v.z; s[k + 3][r] = v.w;
    }
}

// ---------------- 5. out = res + relu(A @ W^T + bias) --------------------
__global__ __launch_bounds__(256, 2) void k_gcn(const float* __restrict__ A,
                                                const float* __restrict__ W,
                                                const float* __restrict__ bias,
                                                const float* __restrict__ res,
                                                float* __restrict__ out) {
    int rt = blockIdx.x << 7;
    const float* Ab = A + (size_t)rt * DD;
    __shared__ float As[64][132];
    __shared__ float Bs[64][132];
    int tid = threadIdx.x;
    int tr  = (tid >> 4) << 3;
    int tc  = (tid & 15) << 3;

    float acc[8][8];
#pragma unroll
    for (int i = 0; i < 8; ++i)
#pragma unroll
        for (int j = 0; j < 8; ++j) acc[i][j] = 0.f;

#pragma unroll
    for (int kc = 0; kc < 2; ++kc) {
        if (kc) __syncthreads();
        stage_T64(Ab + kc * 64, As, tid);
        stage_T64(W + kc * 64, Bs, tid);
        __syncthreads();
#pragma unroll 4
        for (int k = 0; k < 64; ++k) {
            const float4 a0 = *reinterpret_cast<const float4*>(&As[k][tr]);
            const float4 a1 = *reinterpret_cast<const float4*>(&As[k][tr + 4]);
            const float4 b0v = *reinterpret_cast<const float4*>(&Bs[k][tc]);
            const float4 b1v = *reinterpret_cast<const float4*>(&Bs[k][tc + 4]);
            const float av[8] = {a0.x, a0.y, a0.z, a0.w, a1.x, a1.y, a1.z, a1.w};
            const float bw[8] = {b0v.x, b0v.y, b0v.z, b0v.w, b1v.x, b1v.y, b1v.z, b1v.w};
#pragma unroll
            for (int ii = 0; ii < 8; ++ii)
#pragma unroll
                for (int jj = 0; jj < 8; ++jj)
                    acc[ii][jj] = fmaf(av[ii], bw[jj], acc[ii][jj]);
        }
    }
    const float4 bz0 = *reinterpret_cast<const float4*>(bias + tc);
    const float4 bz1 = *reinterpret_cast<const float4*>(bias + tc + 4);
    const float bb[8] = {bz0.x, bz0.y, bz0.z, bz0.w, bz1.x, bz1.y, bz1.z, bz1.w};
#pragma unroll
    for (int i = 0; i < 8; ++i) {
        size_t ro = (size_t)(rt + tr + i) * HH + tc;
        const float4 r0 = *reinterpret_cast<const float4*>(res + ro);
        const float4 r1 = *reinterpret_cast<const float4*>(res + ro + 4);
        float4 o0, o1;
        o0.x = r0.x + fmaxf(acc[i][0] + bb[0], 0.f);
        o0.y = r0.y + fmaxf(acc[i][1] + bb[1], 0.f);
        o0.z = r0.z + fmaxf(acc[i][2] + bb[2], 0.f);
        o0.w = r0.w + fmaxf(acc[i][3] + bb[3], 0.f);
        o1.x = r1.x + fmaxf(acc[i][4] + bb[4], 0.f);
        o1.y = r1.y + fmaxf(acc[i][5] + bb[5], 0.f);
        o1.z = r1.z + fmaxf(acc[i][6] + bb[6], 0.f);
        o1.w = r1.w + fmaxf(acc[i][7] + bb[7], 0.f);
        *reinterpret_cast<float4*>(out + ro)     = o0;
        *reinterpret_cast<float4*>(out + ro + 4) = o1;
    }
}

extern "C" void kernel_launch(void* const* d_in, const int* in_sizes, int n_in,
                              void* d_out, int out_size, void* d_ws, size_t ws_size,
                              hipStream_t stream) {
    const float* x  = (const float*)d_in[0];
    const float* W1 = (const float*)d_in[1];
    const float* b1 = (const float*)d_in[2];
    const float* W2 = (const float*)d_in[3];
    const float* b2 = (const float*)d_in[4];
    float* out = (float*)d_out;

    char* ws = (char*)d_ws;
    size_t xn_b  = (size_t)BB * NN * DD * 4;
    size_t agg_b = (size_t)BB * NN * DD * 4;
    size_t idx_b = (size_t)BB * NN * KK * 4;
    float* xn  = (float*)ws;            ws += xn_b;
    float* agg = (float*)ws;            ws += agg_b;
    int*   idx = (int*)ws;              ws += idx_b;
    float* sim = (float*)ws;
    size_t fixed = xn_b + agg_b + idx_b;
    size_t sim_avail = (ws_size > fixed) ? (ws_size - fixed) : 0;
    int SB = (int)(sim_avail / ((size_t)NN * NN * 4));
    if (SB > BB) SB = BB;
    if (SB < 1) SB = 1;

    k_norm<<<BB * NN / 4, 256, 0, stream>>>(x, xn);
    for (int b0 = 0; b0 < BB; b0 += SB) {
        int sb = (SB < BB - b0) ? SB : (BB - b0);
        k_sim<<<sb * 36, 256, 0, stream>>>(xn, sim, b0);
        k_topk<<<sb * NN / 4, 256, 0, stream>>>(sim, idx, b0);
    }
    k_agg<<<BB * NN / 2, 256, 0, stream>>>(x, idx, agg);
    k_gcn<<<BB * NN / 128, 256, 0, stream>>>(agg, W1, b1, x, out);
    k_agg<<<BB * NN / 2, 256, 0, stream>>>(out, idx, agg);
    k_gcn<<<BB * NN / 128, 256, 0, stream>>>(agg, W2, b2, out, out);
}

// Round 3
// 197.007 us; speedup vs baseline: 1.2143x; 1.0657x over previous
//
#include <hip/hip_runtime.h>
#include <float.h>
#include <math.h>

#define BB 32
#define NN 1024
#define DD 128
#define HH 128
#define KK 5

// bank-conflict-free column swizzle: logical col c -> physical col
// SW(c) = c + 4*(c>>5); spreads 16 col-group float4 reads over all 8
// bank-groups (2-way = free) instead of 4 (4-way). Width 140.
#define SW(c) ((c) + 4 * ((c) >> 5))
#define LDW 140

// ---------------- 1. row L2-normalize: xn = x / max(||x||, 1e-12) --------
__global__ __launch_bounds__(256) void k_norm(const float* __restrict__ x,
                                              float* __restrict__ xn) {
    int row  = blockIdx.x * 4 + (threadIdx.x >> 6);
    int lane = threadIdx.x & 63;
    const float* xr = x + (size_t)row * DD;
    float2 v = *reinterpret_cast<const float2*>(xr + lane * 2);
    float ss = v.x * v.x + v.y * v.y;
#pragma unroll
    for (int o = 32; o >= 1; o >>= 1) ss += __shfl_xor(ss, o);
    float inv = 1.0f / fmaxf(sqrtf(ss), 1e-12f);
    float2 ov = make_float2(v.x * inv, v.y * inv);
    *reinterpret_cast<float2*>(xn + (size_t)row * DD + lane * 2) = ov;
}

// ------- k_sim staging: 128 rows x 32 k, register prefetch + ds_write ----
__device__ __forceinline__ void ld32(const float* __restrict__ g, int tid,
                                     int kc, float4* r) {
    int kv = tid & 7;
    int r0 = tid >> 3;
#pragma unroll
    for (int p = 0; p < 4; ++p)
        r[p] = *reinterpret_cast<const float4*>(g + (size_t)(r0 + (p << 5)) * DD +
                                                (kc << 5) + (kv << 2));
}

__device__ __forceinline__ void st32(float (*s)[LDW], int tid, const float4* r) {
    int k  = (tid & 7) << 2;
    int r0 = tid >> 3;
#pragma unroll
    for (int p = 0; p < 4; ++p) {
        int row = SW(r0 + (p << 5));
        s[k + 0][row] = r[p].x; s[k + 1][row] = r[p].y;
        s[k + 2][row] = r[p].z; s[k + 3][row] = r[p].w;
    }
}

// ---- 2. sim = xn_b . xn_b^T, symmetric: 36 upper-tri 128x128 tiles ------
__global__ __launch_bounds__(256, 4) void k_sim(const float* __restrict__ xn,
                                                float* __restrict__ sim, int b0) {
    int t  = blockIdx.x;
    int bl = t / 36;
    int p  = t - bl * 36;
    int ti = 0;
    while (p >= 8 - ti) { p -= 8 - ti; ++ti; }
    int tj = ti + p;
    int rt = ti << 7, ct = tj << 7;

    const float* Ab = xn + ((size_t)(b0 + bl) * NN + rt) * DD;
    const float* Bb = xn + ((size_t)(b0 + bl) * NN + ct) * DD;
    float* Cb = sim + (size_t)bl * NN * NN;

    __shared__ float As[32][LDW];
    __shared__ float Bs[32][LDW];
    int tid = threadIdx.x;
    int tr  = (tid >> 4) << 3;
    int tc  = (tid & 15) << 3;
    int str = SW(tr);            // swizzled bases (SW(t+4)=SW(t)+4 here)
    int stc = SW(tc);

    float acc[8][8];
#pragma unroll
    for (int i = 0; i < 8; ++i)
#pragma unroll
        for (int j = 0; j < 8; ++j) acc[i][j] = 0.f;

    float4 pa[4], pb[4];
    ld32(Ab, tid, 0, pa);
    ld32(Bb, tid, 0, pb);

#pragma unroll
    for (int kc = 0; kc < 4; ++kc) {
        st32(As, tid, pa);
        st32(Bs, tid, pb);
        __syncthreads();
        if (kc < 3) {
            ld32(Ab, tid, kc + 1, pa);
            ld32(Bb, tid, kc + 1, pb);
        }
#pragma unroll 4
        for (int k = 0; k < 32; ++k) {
            const float4 a0 = *reinterpret_cast<const float4*>(&As[k][str]);
            const float4 a1 = *reinterpret_cast<const float4*>(&As[k][str + 4]);
            const float4 b0v = *reinterpret_cast<const float4*>(&Bs[k][stc]);
            const float4 b1v = *reinterpret_cast<const float4*>(&Bs[k][stc + 4]);
            const float av[8] = {a0.x, a0.y, a0.z, a0.w, a1.x, a1.y, a1.z, a1.w};
            const float bw[8] = {b0v.x, b0v.y, b0v.z, b0v.w, b1v.x, b1v.y, b1v.z, b1v.w};
#pragma unroll
            for (int ii = 0; ii < 8; ++ii)
#pragma unroll
                for (int jj = 0; jj < 8; ++jj)
                    acc[ii][jj] = fmaf(av[ii], bw[jj], acc[ii][jj]);
        }
        __syncthreads();
    }

#pragma unroll
    for (int i = 0; i < 8; ++i) {
        float* cr = Cb + (size_t)(rt + tr + i) * NN + ct + tc;
        *reinterpret_cast<float4*>(cr)     = make_float4(acc[i][0], acc[i][1], acc[i][2], acc[i][3]);
        *reinterpret_cast<float4*>(cr + 4) = make_float4(acc[i][4], acc[i][5], acc[i][6], acc[i][7]);
    }
    if (ti != tj) {
#pragma unroll
        for (int j = 0; j < 8; ++j) {
            float* cr = Cb + (size_t)(ct + tc + j) * NN + rt + tr;
            *reinterpret_cast<float4*>(cr)     = make_float4(acc[0][j], acc[1][j], acc[2][j], acc[3][j]);
            *reinterpret_cast<float4*>(cr + 4) = make_float4(acc[4][j], acc[5][j], acc[6][j], acc[7][j]);
        }
    }
}

// ---------------- 3. top-5 per row (wave per row) ------------------------
__global__ __launch_bounds__(256) void k_topk(const float* __restrict__ sim,
                                              int* __restrict__ idx, int b0) {
    int lrow = blockIdx.x * 4 + (threadIdx.x >> 6);
    int lane = threadIdx.x & 63;
    const float* sr = sim + (size_t)lrow * NN;
    int i = lrow & (NN - 1);

    float v[16];
#pragma unroll
    for (int q = 0; q < 4; ++q) {
        float4 f = *reinterpret_cast<const float4*>(sr + lane * 16 + q * 4);
        v[q * 4 + 0] = f.x; v[q * 4 + 1] = f.y; v[q * 4 + 2] = f.z; v[q * 4 + 3] = f.w;
    }
    if ((i >> 4) == lane) {
        int s = i & 15;
#pragma unroll
        for (int j = 0; j < 16; ++j) if (j == s) v[j] = -FLT_MAX;
    }
    int* op = idx + ((size_t)b0 * NN + lrow) * KK;
#pragma unroll
    for (int t = 0; t < KK; ++t) {
        float bv = v[0]; int bj = 0;
#pragma unroll
        for (int j = 1; j < 16; ++j) if (v[j] > bv) { bv = v[j]; bj = j; }
        int bm = (lane << 4) + bj;
#pragma unroll
        for (int o = 1; o < 64; o <<= 1) {
            float ov = __shfl_xor(bv, o);
            int   om = __shfl_xor(bm, o);
            if (ov > bv || (ov == bv && om < bm)) { bv = ov; bm = om; }
        }
        if ((bm >> 4) == lane) {
            int s = bm & 15;
#pragma unroll
            for (int j = 0; j < 16; ++j) if (j == s) v[j] = -FLT_MAX;
        }
        if (lane == 0) op[t] = bm;
    }
}

// ---- 4. fused gcn: out = res + relu( agg(h,idx) @ W^T + bias ) ----------
// aggregation (h_i + sum_knn h_m)/6 happens during A-tile staging.
__device__ __forceinline__ void stage_agg(const float* __restrict__ h,
                                          const int* __restrict__ idx,
                                          int rt, int kc,
                                          float (*s)[LDW], int tid) {
    int kv = tid & 15;                 // f4 within 64-k chunk
    int r0 = tid >> 4;
    int colf = (kc << 6) + (kv << 2);  // absolute feature col
#pragma unroll
    for (int p = 0; p < 8; ++p) {
        int lrow = r0 + (p << 4);
        int grow = rt + lrow;
        const int* ip = idx + (size_t)grow * KK;
        const float* hb = h + (((size_t)grow >> 10) << 10) * DD;
        float4 v = *reinterpret_cast<const float4*>(h + (size_t)grow * DD + colf);
#pragma unroll
        for (int t = 0; t < KK; ++t) {
            const float4 u = *reinterpret_cast<const float4*>(hb + (size_t)ip[t] * DD + colf);
            v.x += u.x; v.y += u.y; v.z += u.z; v.w += u.w;
        }
        const float c = 1.0f / 6.0f;
        int k = kv << 2, row = SW(lrow);
        s[k + 0][row] = v.x * c; s[k + 1][row] = v.y * c;
        s[k + 2][row] = v.z * c; s[k + 3][row] = v.w * c;
    }
}

__device__ __forceinline__ void stage_w(const float* __restrict__ g,
                                        float (*s)[LDW], int tid) {
    int kv = tid & 15;
    int r0 = tid >> 4;
#pragma unroll
    for (int p = 0; p < 8; ++p) {
        int r = r0 + (p << 4);
        const float4 v = *reinterpret_cast<const float4*>(g + (size_t)r * DD + (kv << 2));
        int k = kv << 2, row = SW(r);
        s[k + 0][row] = v.x; s[k + 1][row] = v.y; s[k + 2][row] = v.z; s[k + 3][row] = v.w;
    }
}

__global__ __launch_bounds__(256, 2) void k_gcn(const float* __restrict__ h,
                                                const int* __restrict__ idx,
                                                const float* __restrict__ W,
                                                const float* __restrict__ bias,
                                                const float* __restrict__ res,
                                                float* __restrict__ out) {
    int rt = blockIdx.x << 7;
    __shared__ float As[64][LDW];
    __shared__ float Bs[64][LDW];
    int tid = threadIdx.x;
    int tr  = (tid >> 4) << 3;
    int tc  = (tid & 15) << 3;
    int str = SW(tr);
    int stc = SW(tc);

    float acc[8][8];
#pragma unroll
    for (int i = 0; i < 8; ++i)
#pragma unroll
        for (int j = 0; j < 8; ++j) acc[i][j] = 0.f;

#pragma unroll
    for (int kc = 0; kc < 2; ++kc) {
        if (kc) __syncthreads();
        stage_agg(h, idx, rt, kc, As, tid);
        stage_w(W + kc * 64, Bs, tid);
        __syncthreads();
#pragma unroll 4
        for (int k = 0; k < 64; ++k) {
            const float4 a0 = *reinterpret_cast<const float4*>(&As[k][str]);
            const float4 a1 = *reinterpret_cast<const float4*>(&As[k][str + 4]);
            const float4 b0v = *reinterpret_cast<const float4*>(&Bs[k][stc]);
            const float4 b1v = *reinterpret_cast<const float4*>(&Bs[k][stc + 4]);
            const float av[8] = {a0.x, a0.y, a0.z, a0.w, a1.x, a1.y, a1.z, a1.w};
            const float bw[8] = {b0v.x, b0v.y, b0v.z, b0v.w, b1v.x, b1v.y, b1v.z, b1v.w};
#pragma unroll
            for (int ii = 0; ii < 8; ++ii)
#pragma unroll
                for (int jj = 0; jj < 8; ++jj)
                    acc[ii][jj] = fmaf(av[ii], bw[jj], acc[ii][jj]);
        }
    }
    const float4 bz0 = *reinterpret_cast<const float4*>(bias + tc);
    const float4 bz1 = *reinterpret_cast<const float4*>(bias + tc + 4);
    const float bb[8] = {bz0.x, bz0.y, bz0.z, bz0.w, bz1.x, bz1.y, bz1.z, bz1.w};
#pragma unroll
    for (int i = 0; i < 8; ++i) {
        size_t ro = (size_t)(rt + tr + i) * HH + tc;
        const float4 r0 = *reinterpret_cast<const float4*>(res + ro);
        const float4 r1 = *reinterpret_cast<const float4*>(res + ro + 4);
        float4 o0, o1;
        o0.x = r0.x + fmaxf(acc[i][0] + bb[0], 0.f);
        o0.y = r0.y + fmaxf(acc[i][1] + bb[1], 0.f);
        o0.z = r0.z + fmaxf(acc[i][2] + bb[2], 0.f);
        o0.w = r0.w + fmaxf(acc[i][3] + bb[3], 0.f);
        o1.x = r1.x + fmaxf(acc[i][4] + bb[4], 0.f);
        o1.y = r1.y + fmaxf(acc[i][5] + bb[5], 0.f);
        o1.z = r1.z + fmaxf(acc[i][6] + bb[6], 0.f);
        o1.w = r1.w + fmaxf(acc[i][7] + bb[7], 0.f);
        *reinterpret_cast<float4*>(out + ro)     = o0;
        *reinterpret_cast<float4*>(out + ro + 4) = o1;
    }
}

extern "C" void kernel_launch(void* const* d_in, const int* in_sizes, int n_in,
                              void* d_out, int out_size, void* d_ws, size_t ws_size,
                              hipStream_t stream) {
    const float* x  = (const float*)d_in[0];
    const float* W1 = (const float*)d_in[1];
    const float* b1 = (const float*)d_in[2];
    const float* W2 = (const float*)d_in[3];
    const float* b2 = (const float*)d_in[4];
    float* out = (float*)d_out;

    char* ws = (char*)d_ws;
    size_t xn_b  = (size_t)BB * NN * DD * 4;
    size_t h1_b  = (size_t)BB * NN * DD * 4;
    size_t idx_b = (size_t)BB * NN * KK * 4;
    float* xn  = (float*)ws;            ws += xn_b;
    float* h1  = (float*)ws;            ws += h1_b;
    int*   idx = (int*)ws;              ws += idx_b;
    float* sim = (float*)ws;
    size_t fixed = xn_b + h1_b + idx_b;
    size_t sim_avail = (ws_size > fixed) ? (ws_size - fixed) : 0;
    int SB = (int)(sim_avail / ((size_t)NN * NN * 4));
    if (SB > BB) SB = BB;
    if (SB < 1) SB = 1;

    k_norm<<<BB * NN / 4, 256, 0, stream>>>(x, xn);
    for (int b0 = 0; b0 < BB; b0 += SB) {
        int sb = (SB < BB - b0) ? SB : (BB - b0);
        k_sim<<<sb * 36, 256, 0, stream>>>(xn, sim, b0);
        k_topk<<<sb * NN / 4, 256, 0, stream>>>(sim, idx, b0);
    }
    // layer 1: reads x, writes h1 (ws); layer 2: reads h1, writes d_out.
    k_gcn<<<BB * NN / 128, 256, 0, stream>>>(x,  idx, W1, b1, x,  h1);
    k_gcn<<<BB * NN / 128, 256, 0, stream>>>(h1, idx, W2, b2, h1, out);
}